// Round 3
// baseline (4949.845 us; speedup 1.0000x reference)
//
#include <hip/hip_runtime.h>
#include <math.h>

#define TOKENS 52224   // 512*102
#define SEQL   102
#define EMB    256
#define NH     16
#define DH     16
#define FFD    1024
#define BATCH  512
#define KS     50
#define POFF   1001    // problem_size + 1
#define MCHUNK 13056   // TOKENS/4 for FFN chunking

// ---------------- shared GEMM body: C[M,N] = relu?(A@W + bias) + res? ------
// BM=BN=128, BK=32, 256 threads, 8x8 microtile split at +-64.
template<bool RELU, bool HASBIAS, bool HASRES>
__device__ __forceinline__
void gemm_body(const float* __restrict__ A, int lda,
               const float* __restrict__ W, int ldw,
               const float* __restrict__ bias,
               const float* __restrict__ res, int ldres,
               float* __restrict__ C, int ldc,
               int K, size_t bm, int bn)
{
    __shared__ float As[32][132];   // [k][m] transposed
    __shared__ float Ws[32][132];   // [k][n]
    const int tid = threadIdx.x;
    const int tx = tid & 15;
    const int ty = tid >> 4;

    float acc[8][8];
    #pragma unroll
    for (int i = 0; i < 8; ++i)
        #pragma unroll
        for (int j = 0; j < 8; ++j) acc[i][j] = 0.f;

    for (int k0 = 0; k0 < K; k0 += 32) {
        #pragma unroll
        for (int i = 0; i < 4; ++i) {
            int f = tid + i * 256;
            int m = f >> 3;
            int kq = f & 7;
            const float4 av = *(const float4*)(A + (bm + m) * lda + (k0 + kq * 4));
            As[kq * 4 + 0][m] = av.x;
            As[kq * 4 + 1][m] = av.y;
            As[kq * 4 + 2][m] = av.z;
            As[kq * 4 + 3][m] = av.w;
        }
        #pragma unroll
        for (int i = 0; i < 4; ++i) {
            int f = tid + i * 256;
            int kk = f >> 5;
            int nq = f & 31;
            *(float4*)&Ws[kk][nq * 4] =
                *(const float4*)(W + (size_t)(k0 + kk) * ldw + bn + nq * 4);
        }
        __syncthreads();
        #pragma unroll
        for (int kk = 0; kk < 32; ++kk) {
            float a0[8], b0[8];
            *(float4*)&a0[0] = *(const float4*)&As[kk][ty * 4];
            *(float4*)&a0[4] = *(const float4*)&As[kk][64 + ty * 4];
            *(float4*)&b0[0] = *(const float4*)&Ws[kk][tx * 4];
            *(float4*)&b0[4] = *(const float4*)&Ws[kk][64 + tx * 4];
            #pragma unroll
            for (int i = 0; i < 8; ++i)
                #pragma unroll
                for (int j = 0; j < 8; ++j)
                    acc[i][j] = fmaf(a0[i], b0[j], acc[i][j]);
        }
        __syncthreads();
    }

    #pragma unroll
    for (int ih = 0; ih < 2; ++ih) {
        #pragma unroll
        for (int i2 = 0; i2 < 4; ++i2) {
            const int i = ih * 4 + i2;
            const size_t row = bm + ih * 64 + ty * 4 + i2;
            #pragma unroll
            for (int jh = 0; jh < 2; ++jh) {
                const int colb = bn + jh * 64 + tx * 4;
                float4 vv;
                vv.x = acc[i][jh * 4 + 0];
                vv.y = acc[i][jh * 4 + 1];
                vv.z = acc[i][jh * 4 + 2];
                vv.w = acc[i][jh * 4 + 3];
                if (HASBIAS) {
                    const float4 bb = *(const float4*)(bias + colb);
                    vv.x += bb.x; vv.y += bb.y; vv.z += bb.z; vv.w += bb.w;
                }
                if (RELU) {
                    vv.x = fmaxf(vv.x, 0.f); vv.y = fmaxf(vv.y, 0.f);
                    vv.z = fmaxf(vv.z, 0.f); vv.w = fmaxf(vv.w, 0.f);
                }
                if (HASRES) {
                    const float4 rr = *(const float4*)(res + row * ldres + colb);
                    vv.x += rr.x; vv.y += rr.y; vv.z += rr.z; vv.w += rr.w;
                }
                *(float4*)(C + row * ldc + colb) = vv;
            }
        }
    }
}

template<bool RELU, bool HASBIAS, bool HASRES>
__global__ __launch_bounds__(256, 2)
void gemm_k(const float* __restrict__ A, int lda,
            const float* __restrict__ W, int ldw,
            const float* __restrict__ bias,
            const float* __restrict__ res, int ldres,
            float* __restrict__ C, int ldc, int K)
{
    gemm_body<RELU, HASBIAS, HASRES>(A, lda, W, ldw, bias, res, ldres, C, ldc,
                                     K, (size_t)blockIdx.x * 128, blockIdx.y * 128);
}

// Fused QKV: grid (TOKENS/128, 6); blockIdx.y>>1 selects {Wq,Wk,Wv}.
__global__ __launch_bounds__(256, 2)
void qkv_k(const float* __restrict__ x,
           const float* __restrict__ wq, const float* __restrict__ wk,
           const float* __restrict__ wv,
           float* __restrict__ q, float* __restrict__ k, float* __restrict__ v)
{
    const int wi = blockIdx.y >> 1;
    const int bn = (blockIdx.y & 1) * 128;
    const float* W = (wi == 0) ? wq : (wi == 1) ? wk : wv;
    float* C = (wi == 0) ? q : (wi == 1) ? k : v;
    gemm_body<false, false, false>(x, EMB, W, EMB, nullptr, nullptr, 0, C, EMB,
                                   EMB, (size_t)blockIdx.x * 128, bn);
}

// ---------------- preprocess copy: knn rows passthrough ----------------
__global__ __launch_bounds__(256)
void pre_copy_k(const float* __restrict__ xin, float* __restrict__ x0)
{
    int idx = blockIdx.x * 256 + threadIdx.x;   // float4 index, total 512*100*64
    int c = idx & 63;
    int r = idx >> 6;
    int si = r % 100;
    int b = r / 100;
    int s = (si < 50) ? si + 1 : si + 2;        // dest seq pos (skip 0 and 51)
    const float4 v = *(const float4*)(xin + ((size_t)b * SEQL + (s - 1)) * EMB + c * 4);
    *(float4*)(x0 + ((size_t)b * SEQL + s) * EMB + c * 4) = v;
}

// ---------------- attention: one block per (batch, head) ----------------
// NOTE: o may alias q — each block reads only its own (b,h) slice (fully
// staged to LDS before any global write) and writes only that same slice.
__global__ __launch_bounds__(256)
void attn_k(const float* __restrict__ q, const float* __restrict__ k,
            const float* __restrict__ v, float* __restrict__ o)
{
    const int b = blockIdx.x, h = blockIdx.y;
    __shared__ float qs[SEQL][DH], ks[SEQL][DH], vs[SEQL][DH];
    __shared__ float sc[SEQL][SEQL + 1];
    const size_t base = (size_t)b * SEQL * EMB + h * DH;
    const int tid = threadIdx.x;

    for (int idx = tid; idx < SEQL * DH; idx += 256) {
        int s = idx >> 4, d = idx & 15;
        qs[s][d] = q[base + (size_t)s * EMB + d];
        ks[s][d] = k[base + (size_t)s * EMB + d];
        vs[s][d] = v[base + (size_t)s * EMB + d];
    }
    __syncthreads();
    for (int e = tid; e < SEQL * SEQL; e += 256) {
        int m = e / SEQL, n = e - m * SEQL;
        float s = 0.f;
        #pragma unroll
        for (int d = 0; d < DH; ++d) s = fmaf(qs[m][d], ks[n][d], s);
        sc[m][n] = s * 0.25f;   // 1/sqrt(16)
    }
    __syncthreads();
    if (tid < SEQL) {
        float mx = -1e30f;
        for (int n = 0; n < SEQL; ++n) mx = fmaxf(mx, sc[tid][n]);
        float sum = 0.f;
        for (int n = 0; n < SEQL; ++n) {
            float e2 = expf(sc[tid][n] - mx);
            sc[tid][n] = e2;
            sum += e2;
        }
        float inv = 1.f / sum;
        for (int n = 0; n < SEQL; ++n) sc[tid][n] *= inv;
    }
    __syncthreads();
    for (int e = tid; e < SEQL * DH; e += 256) {
        int m = e >> 4, d = e & 15;
        float s = 0.f;
        for (int n = 0; n < SEQL; ++n) s = fmaf(sc[m][n], vs[n][d], s);
        o[base + (size_t)m * EMB + d] = s;
    }
}

// ---------------- logits: one wave per token ----------------
__global__ __launch_bounds__(256)
void logits_k(const float* __restrict__ x, const float* __restrict__ Wf,
              const float* __restrict__ bf, float* __restrict__ logits)
{
    const int t = blockIdx.x * 4 + (threadIdx.x >> 6);
    const int lane = threadIdx.x & 63;
    const float* row = x + (size_t)t * EMB;
    float s = 0.f;
    #pragma unroll
    for (int i = 0; i < 4; ++i) s = fmaf(row[lane + i * 64], Wf[lane + i * 64], s);
    #pragma unroll
    for (int off = 32; off > 0; off >>= 1) s += __shfl_down(s, off);
    if (lane == 0) logits[t] = s + bf[0];
}

// ---------------- final masked softmax + scatter ----------------
__global__ __launch_bounds__(128)
void final_k(const float* __restrict__ logits, const float* __restrict__ mask,
             const int* __restrict__ lastl, const int* __restrict__ depotl,
             float* __restrict__ out)
{
    const int b = blockIdx.x;
    const int tid = threadIdx.x;
    __shared__ float ls[SEQL];
    __shared__ float red[2];
    float v = 0.f;
    if (tid < SEQL) {
        v = logits[b * SEQL + tid];
        if (tid == 0 || tid == 51) v = -1e30f;
        else if (tid <= 50) v += mask[b * KS + (tid - 1)];
        ls[tid] = v;
    }
    __syncthreads();
    if (tid < 64) {
        float m = ls[tid];
        if (tid + 64 < SEQL) m = fmaxf(m, ls[tid + 64]);
        #pragma unroll
        for (int off = 32; off > 0; off >>= 1) m = fmaxf(m, __shfl_down(m, off));
        if (tid == 0) red[0] = m;
    }
    __syncthreads();
    const float mx = red[0];
    if (tid < SEQL) {
        float e = (tid == 0 || tid == 51) ? 0.f : expf(v - mx);
        ls[tid] = e;
    }
    __syncthreads();
    if (tid < 64) {
        float s2 = ls[tid];
        if (tid + 64 < SEQL) s2 += ls[tid + 64];
        #pragma unroll
        for (int off = 32; off > 0; off >>= 1) s2 += __shfl_down(s2, off);
        if (tid == 0) red[1] = s2;
    }
    __syncthreads();
    const float sum = red[1];
    float* orow = out + (size_t)b * 2002;
    for (int j = tid; j < 2002; j += 128) orow[j] = 1e-20f;
    __syncthreads();
    if (tid < SEQL && tid != 0 && tid != 51) {
        float p = ls[tid] / sum;
        if (p <= 1e-5f) p += 1e-7f;
        int col;
        if (tid <= 50) col = lastl[b * KS + (tid - 1)];
        else           col = POFF + depotl[b * KS + (tid - 52)];
        orow[col] = p;
    }
}

extern "C" void kernel_launch(void* const* d_in, const int* in_sizes, int n_in,
                              void* d_out, int out_size, void* d_ws, size_t ws_size,
                              hipStream_t stream)
{
    const float* xin  = (const float*)d_in[0];
    const float* mask = (const float*)d_in[1];
    const float* Wnv  = (const float*)d_in[2];
    const float* bnv  = (const float*)d_in[3];
    const float* Wvp  = (const float*)d_in[4];
    const float* bvp  = (const float*)d_in[5];
    const float* Wq   = (const float*)d_in[6];
    const float* Wk   = (const float*)d_in[7];
    const float* Wv   = (const float*)d_in[8];
    const float* Wc   = (const float*)d_in[9];
    const float* bc   = (const float*)d_in[10];
    const float* W1   = (const float*)d_in[11];
    const float* b1   = (const float*)d_in[12];
    const float* W2   = (const float*)d_in[13];
    const float* b2   = (const float*)d_in[14];
    const float* Wf   = (const float*)d_in[15];
    const float* bfp  = (const float*)d_in[16];
    const int* lastl  = (const int*)d_in[17];
    const int* depotl = (const int*)d_in[18];
    float* out = (float*)d_out;

    // Workspace: 4 activation slots (53.5 MB each) + logits  =>  ~214 MB
    float* ws = (float*)d_ws;
    const size_t S = (size_t)TOKENS * EMB;
    float* s0 = ws + 0 * S;   // x (layer input & output)
    float* s1 = ws + 1 * S;   // q, then o (aliased)
    float* s2 = ws + 2 * S;   // k, then out1
    float* s3 = ws + 3 * S;   // v, then ff chunk (13056*1024 == S)
    float* logits = ws + 4 * S;

    const dim3 blk(256);

    // ---- preprocess: x0 = concat([last_nv@Wnv+b, knn_nv, last_v@Wv+b, knn_v])
    pre_copy_k<<<BATCH * 100 * 64 / 256, 256, 0, stream>>>(xin, s0);
    {
        dim3 g(BATCH / 128, EMB / 128);
        gemm_k<false, true, false><<<g, blk, 0, stream>>>(
            xin + 50 * EMB, SEQL * EMB, Wnv, EMB, bnv, nullptr, 0, s0 + 0 * EMB, SEQL * EMB, EMB);
        gemm_k<false, true, false><<<g, blk, 0, stream>>>(
            xin + 101 * EMB, SEQL * EMB, Wvp, EMB, bvp, nullptr, 0, s0 + 51 * EMB, SEQL * EMB, EMB);
    }

    const dim3 g256(TOKENS / 128, EMB / 128);     // (408, 2)
    const dim3 gqkv(TOKENS / 128, 6);             // (408, 6)
    const dim3 gff1(MCHUNK / 128, FFD / 128);     // (102, 8)
    const dim3 gff2(MCHUNK / 128, EMB / 128);     // (102, 2)
    for (int l = 0; l < 3; ++l) {
        const float* wq  = Wq + (size_t)l * EMB * EMB;
        const float* wk  = Wk + (size_t)l * EMB * EMB;
        const float* wv  = Wv + (size_t)l * EMB * EMB;
        const float* wc  = Wc + (size_t)l * EMB * EMB;
        const float* bcl = bc + (size_t)l * EMB;
        const float* w1  = W1 + (size_t)l * EMB * FFD;
        const float* b1l = b1 + (size_t)l * FFD;
        const float* w2  = W2 + (size_t)l * FFD * EMB;
        const float* b2l = b2 + (size_t)l * EMB;

        qkv_k<<<gqkv, blk, 0, stream>>>(s0, wq, wk, wv, s1, s2, s3);

        attn_k<<<dim3(BATCH, NH), blk, 0, stream>>>(s1, s2, s3, s1);  // o aliases q

        // out1 = x + o@Wc + bc  -> s2 (k dead)
        gemm_k<false, true, true><<<g256, blk, 0, stream>>>(
            s1, EMB, wc, EMB, bcl, s0, EMB, s2, EMB, EMB);

        // FFN in 4 token chunks; ff intermediate reuses s3 (v dead).
        // x_next -> s0 (x dead after residual consumed above)
        for (int c = 0; c < 4; ++c) {
            const size_t moff = (size_t)c * MCHUNK;
            gemm_k<true, true, false><<<gff1, blk, 0, stream>>>(
                s2 + moff * EMB, EMB, w1, FFD, b1l, nullptr, 0, s3, FFD, EMB);
            gemm_k<false, true, true><<<gff2, blk, 0, stream>>>(
                s3, FFD, w2, EMB, b2l, s2 + moff * EMB, EMB, s0 + moff * EMB, EMB, FFD);
        }
    }

    logits_k<<<TOKENS / 4, 256, 0, stream>>>(s0, Wf, bfp, logits);
    final_k<<<BATCH, 128, 0, stream>>>(logits, mask, lastl, depotl, out);
}

// Round 4
// 4513.147 us; speedup vs baseline: 1.0968x; 1.0968x over previous
//
#include <hip/hip_runtime.h>
#include <math.h>

#define TOKENS 52224   // 512*102
#define SEQL   102
#define EMB    256
#define NH     16
#define DH     16
#define FFD    1024
#define BATCH  512
#define KS     50
#define POFF   1001    // problem_size + 1
#define MCHUNK 13056   // TOKENS/4 for FFN chunking
#define SCW    108     // sc row stride: 108%32=12 -> 8-bank spread on row-broadcast reads

// ---------------- shared GEMM body: C[M,N] = relu?(A@W + bias) + res? ------
// BM=BN=128, BK=32, 256 threads, 8x8 microtile split at +-64.
template<bool RELU, bool HASBIAS, bool HASRES>
__device__ __forceinline__
void gemm_body(const float* __restrict__ A, int lda,
               const float* __restrict__ W, int ldw,
               const float* __restrict__ bias,
               const float* __restrict__ res, int ldres,
               float* __restrict__ C, int ldc,
               int K, size_t bm, int bn)
{
    __shared__ float As[32][132];   // [k][m] transposed
    __shared__ float Ws[32][132];   // [k][n]
    const int tid = threadIdx.x;
    const int tx = tid & 15;
    const int ty = tid >> 4;

    float acc[8][8];
    #pragma unroll
    for (int i = 0; i < 8; ++i)
        #pragma unroll
        for (int j = 0; j < 8; ++j) acc[i][j] = 0.f;

    for (int k0 = 0; k0 < K; k0 += 32) {
        #pragma unroll
        for (int i = 0; i < 4; ++i) {
            int f = tid + i * 256;
            int m = f >> 3;
            int kq = f & 7;
            const float4 av = *(const float4*)(A + (bm + m) * lda + (k0 + kq * 4));
            As[kq * 4 + 0][m] = av.x;
            As[kq * 4 + 1][m] = av.y;
            As[kq * 4 + 2][m] = av.z;
            As[kq * 4 + 3][m] = av.w;
        }
        #pragma unroll
        for (int i = 0; i < 4; ++i) {
            int f = tid + i * 256;
            int kk = f >> 5;
            int nq = f & 31;
            *(float4*)&Ws[kk][nq * 4] =
                *(const float4*)(W + (size_t)(k0 + kk) * ldw + bn + nq * 4);
        }
        __syncthreads();
        #pragma unroll
        for (int kk = 0; kk < 32; ++kk) {
            float a0[8], b0[8];
            *(float4*)&a0[0] = *(const float4*)&As[kk][ty * 4];
            *(float4*)&a0[4] = *(const float4*)&As[kk][64 + ty * 4];
            *(float4*)&b0[0] = *(const float4*)&Ws[kk][tx * 4];
            *(float4*)&b0[4] = *(const float4*)&Ws[kk][64 + tx * 4];
            #pragma unroll
            for (int i = 0; i < 8; ++i)
                #pragma unroll
                for (int j = 0; j < 8; ++j)
                    acc[i][j] = fmaf(a0[i], b0[j], acc[i][j]);
        }
        __syncthreads();
    }

    #pragma unroll
    for (int ih = 0; ih < 2; ++ih) {
        #pragma unroll
        for (int i2 = 0; i2 < 4; ++i2) {
            const int i = ih * 4 + i2;
            const size_t row = bm + ih * 64 + ty * 4 + i2;
            #pragma unroll
            for (int jh = 0; jh < 2; ++jh) {
                const int colb = bn + jh * 64 + tx * 4;
                float4 vv;
                vv.x = acc[i][jh * 4 + 0];
                vv.y = acc[i][jh * 4 + 1];
                vv.z = acc[i][jh * 4 + 2];
                vv.w = acc[i][jh * 4 + 3];
                if (HASBIAS) {
                    const float4 bb = *(const float4*)(bias + colb);
                    vv.x += bb.x; vv.y += bb.y; vv.z += bb.z; vv.w += bb.w;
                }
                if (RELU) {
                    vv.x = fmaxf(vv.x, 0.f); vv.y = fmaxf(vv.y, 0.f);
                    vv.z = fmaxf(vv.z, 0.f); vv.w = fmaxf(vv.w, 0.f);
                }
                if (HASRES) {
                    const float4 rr = *(const float4*)(res + row * ldres + colb);
                    vv.x += rr.x; vv.y += rr.y; vv.z += rr.z; vv.w += rr.w;
                }
                *(float4*)(C + row * ldc + colb) = vv;
            }
        }
    }
}

template<bool RELU, bool HASBIAS, bool HASRES>
__global__ __launch_bounds__(256, 2)
void gemm_k(const float* __restrict__ A, int lda,
            const float* __restrict__ W, int ldw,
            const float* __restrict__ bias,
            const float* __restrict__ res, int ldres,
            float* __restrict__ C, int ldc, int K)
{
    gemm_body<RELU, HASBIAS, HASRES>(A, lda, W, ldw, bias, res, ldres, C, ldc,
                                     K, (size_t)blockIdx.x * 128, blockIdx.y * 128);
}

// Fused QKV: grid (TOKENS/128, 6); blockIdx.y>>1 selects {Wq,Wk,Wv}.
__global__ __launch_bounds__(256, 2)
void qkv_k(const float* __restrict__ x,
           const float* __restrict__ wq, const float* __restrict__ wk,
           const float* __restrict__ wv,
           float* __restrict__ q, float* __restrict__ k, float* __restrict__ v)
{
    const int wi = blockIdx.y >> 1;
    const int bn = (blockIdx.y & 1) * 128;
    const float* W = (wi == 0) ? wq : (wi == 1) ? wk : wv;
    float* C = (wi == 0) ? q : (wi == 1) ? k : v;
    gemm_body<false, false, false>(x, EMB, W, EMB, nullptr, nullptr, 0, C, EMB,
                                   EMB, (size_t)blockIdx.x * 128, bn);
}

// ---------------- preprocess copy: knn rows passthrough ----------------
__global__ __launch_bounds__(256)
void pre_copy_k(const float* __restrict__ xin, float* __restrict__ x0)
{
    int idx = blockIdx.x * 256 + threadIdx.x;   // float4 index, total 512*100*64
    int c = idx & 63;
    int r = idx >> 6;
    int si = r % 100;
    int b = r / 100;
    int s = (si < 50) ? si + 1 : si + 2;        // dest seq pos (skip 0 and 51)
    const float4 v = *(const float4*)(xin + ((size_t)b * SEQL + (s - 1)) * EMB + c * 4);
    *(float4*)(x0 + ((size_t)b * SEQL + s) * EMB + c * 4) = v;
}

// ---------------- attention: one block per (batch, head) ----------------
// Conflict-free layout: K transposed (ksT[d][n], consecutive-n float4 reads),
// sc rows padded to 108 (12-bank offset per row), wave-parallel softmax
// (8 groups x 32 lanes, shfl_xor reductions).
// NOTE: o may alias q — all global reads complete (load phase + barrier)
// before any global write; blocks touch disjoint (b,h) slices.
__global__ __launch_bounds__(256)
void attn_k(const float* __restrict__ q, const float* __restrict__ k,
            const float* __restrict__ v, float* __restrict__ o)
{
    const int b = blockIdx.x, h = blockIdx.y;
    __shared__ float qs[SEQL][DH];     // pre-scaled by 0.25
    __shared__ float ksT[DH][104];     // transposed; cols 102-103 zeroed
    __shared__ float vs[SEQL][DH];
    __shared__ float sc[SEQL][SCW];
    const size_t base = (size_t)b * SEQL * EMB + h * DH;
    const int tid = threadIdx.x;

    for (int idx = tid; idx < SEQL * DH; idx += 256) {
        int s = idx >> 4, d = idx & 15;
        float kv = k[base + (size_t)s * EMB + d];
        qs[s][d] = q[base + (size_t)s * EMB + d] * 0.25f;
        vs[s][d] = v[base + (size_t)s * EMB + d];
        ksT[d][s] = kv;
    }
    if (tid < DH * 2) {                 // zero the padding cols
        ksT[tid >> 1][SEQL + (tid & 1)] = 0.f;
    }
    __syncthreads();

    // ---- QK^T: rows (mp, mp+51), col quad nq; 8 FMA per b128 ----
    for (int t = tid; t < 51 * 26; t += 256) {
        int mp = t / 26;
        int n0 = (t - mp * 26) * 4;
        float4 a0 = {0.f, 0.f, 0.f, 0.f};
        float4 a1 = {0.f, 0.f, 0.f, 0.f};
        #pragma unroll
        for (int d = 0; d < DH; ++d) {
            const float4 kv = *(const float4*)&ksT[d][n0];
            const float q0 = qs[mp][d];
            const float q1 = qs[mp + 51][d];
            a0.x = fmaf(q0, kv.x, a0.x); a0.y = fmaf(q0, kv.y, a0.y);
            a0.z = fmaf(q0, kv.z, a0.z); a0.w = fmaf(q0, kv.w, a0.w);
            a1.x = fmaf(q1, kv.x, a1.x); a1.y = fmaf(q1, kv.y, a1.y);
            a1.z = fmaf(q1, kv.z, a1.z); a1.w = fmaf(q1, kv.w, a1.w);
        }
        *(float4*)&sc[mp][n0] = a0;
        *(float4*)&sc[mp + 51][n0] = a1;
    }
    __syncthreads();

    // ---- softmax: one row per 32-lane group ----
    {
        const int grp = tid >> 5;
        const int lane = tid & 31;
        for (int m = grp; m < SEQL; m += 8) {
            float v0 = sc[m][lane];
            float v1 = sc[m][lane + 32];
            float v2 = sc[m][lane + 64];
            float v3 = (lane < SEQL - 96) ? sc[m][lane + 96] : -1e30f;
            float mx = fmaxf(fmaxf(v0, v1), fmaxf(v2, v3));
            #pragma unroll
            for (int s2 = 16; s2 > 0; s2 >>= 1) mx = fmaxf(mx, __shfl_xor(mx, s2));
            float e0 = __expf(v0 - mx);
            float e1 = __expf(v1 - mx);
            float e2 = __expf(v2 - mx);
            float e3 = (lane < SEQL - 96) ? __expf(v3 - mx) : 0.f;
            float sm = e0 + e1 + e2 + e3;
            #pragma unroll
            for (int s2 = 16; s2 > 0; s2 >>= 1) sm += __shfl_xor(sm, s2);
            const float inv = 1.f / sm;
            sc[m][lane] = e0 * inv;
            sc[m][lane + 32] = e1 * inv;
            sc[m][lane + 64] = e2 * inv;
            if (lane < SEQL - 96) sc[m][lane + 96] = e3 * inv;
        }
    }
    __syncthreads();

    // ---- PV: rows (mp, mp+51), d quad; 8 FMA per b128 ----
    for (int t = tid; t < 51 * 4; t += 256) {
        int mp = t >> 2;
        int d0 = (t & 3) * 4;
        float4 a0 = {0.f, 0.f, 0.f, 0.f};
        float4 a1 = {0.f, 0.f, 0.f, 0.f};
        for (int n = 0; n < SEQL; ++n) {
            const float4 vv = *(const float4*)&vs[n][d0];
            const float p0 = sc[mp][n];
            const float p1 = sc[mp + 51][n];
            a0.x = fmaf(p0, vv.x, a0.x); a0.y = fmaf(p0, vv.y, a0.y);
            a0.z = fmaf(p0, vv.z, a0.z); a0.w = fmaf(p0, vv.w, a0.w);
            a1.x = fmaf(p1, vv.x, a1.x); a1.y = fmaf(p1, vv.y, a1.y);
            a1.z = fmaf(p1, vv.z, a1.z); a1.w = fmaf(p1, vv.w, a1.w);
        }
        *(float4*)(o + base + (size_t)mp * EMB + d0) = a0;
        *(float4*)(o + base + (size_t)(mp + 51) * EMB + d0) = a1;
    }
}

// ---------------- logits: one wave per token ----------------
__global__ __launch_bounds__(256)
void logits_k(const float* __restrict__ x, const float* __restrict__ Wf,
              const float* __restrict__ bf, float* __restrict__ logits)
{
    const int t = blockIdx.x * 4 + (threadIdx.x >> 6);
    const int lane = threadIdx.x & 63;
    const float* row = x + (size_t)t * EMB;
    float s = 0.f;
    #pragma unroll
    for (int i = 0; i < 4; ++i) s = fmaf(row[lane + i * 64], Wf[lane + i * 64], s);
    #pragma unroll
    for (int off = 32; off > 0; off >>= 1) s += __shfl_down(s, off);
    if (lane == 0) logits[t] = s + bf[0];
}

// ---------------- final masked softmax + scatter ----------------
__global__ __launch_bounds__(128)
void final_k(const float* __restrict__ logits, const float* __restrict__ mask,
             const int* __restrict__ lastl, const int* __restrict__ depotl,
             float* __restrict__ out)
{
    const int b = blockIdx.x;
    const int tid = threadIdx.x;
    __shared__ float ls[SEQL];
    __shared__ float red[2];
    float v = 0.f;
    if (tid < SEQL) {
        v = logits[b * SEQL + tid];
        if (tid == 0 || tid == 51) v = -1e30f;
        else if (tid <= 50) v += mask[b * KS + (tid - 1)];
        ls[tid] = v;
    }
    __syncthreads();
    if (tid < 64) {
        float m = ls[tid];
        if (tid + 64 < SEQL) m = fmaxf(m, ls[tid + 64]);
        #pragma unroll
        for (int off = 32; off > 0; off >>= 1) m = fmaxf(m, __shfl_down(m, off));
        if (tid == 0) red[0] = m;
    }
    __syncthreads();
    const float mx = red[0];
    if (tid < SEQL) {
        float e = (tid == 0 || tid == 51) ? 0.f : expf(v - mx);
        ls[tid] = e;
    }
    __syncthreads();
    if (tid < 64) {
        float s2 = ls[tid];
        if (tid + 64 < SEQL) s2 += ls[tid + 64];
        #pragma unroll
        for (int off = 32; off > 0; off >>= 1) s2 += __shfl_down(s2, off);
        if (tid == 0) red[1] = s2;
    }
    __syncthreads();
    const float sum = red[1];
    float* orow = out + (size_t)b * 2002;
    for (int j = tid; j < 2002; j += 128) orow[j] = 1e-20f;
    __syncthreads();
    if (tid < SEQL && tid != 0 && tid != 51) {
        float p = ls[tid] / sum;
        if (p <= 1e-5f) p += 1e-7f;
        int col;
        if (tid <= 50) col = lastl[b * KS + (tid - 1)];
        else           col = POFF + depotl[b * KS + (tid - 52)];
        orow[col] = p;
    }
}

extern "C" void kernel_launch(void* const* d_in, const int* in_sizes, int n_in,
                              void* d_out, int out_size, void* d_ws, size_t ws_size,
                              hipStream_t stream)
{
    const float* xin  = (const float*)d_in[0];
    const float* mask = (const float*)d_in[1];
    const float* Wnv  = (const float*)d_in[2];
    const float* bnv  = (const float*)d_in[3];
    const float* Wvp  = (const float*)d_in[4];
    const float* bvp  = (const float*)d_in[5];
    const float* Wq   = (const float*)d_in[6];
    const float* Wk   = (const float*)d_in[7];
    const float* Wv   = (const float*)d_in[8];
    const float* Wc   = (const float*)d_in[9];
    const float* bc   = (const float*)d_in[10];
    const float* W1   = (const float*)d_in[11];
    const float* b1   = (const float*)d_in[12];
    const float* W2   = (const float*)d_in[13];
    const float* b2   = (const float*)d_in[14];
    const float* Wf   = (const float*)d_in[15];
    const float* bfp  = (const float*)d_in[16];
    const int* lastl  = (const int*)d_in[17];
    const int* depotl = (const int*)d_in[18];
    float* out = (float*)d_out;

    // Workspace: 4 activation slots (53.5 MB each) + logits  =>  ~214 MB
    float* ws = (float*)d_ws;
    const size_t S = (size_t)TOKENS * EMB;
    float* s0 = ws + 0 * S;   // x (layer input & output)
    float* s1 = ws + 1 * S;   // q, then o (aliased)
    float* s2 = ws + 2 * S;   // k, then out1
    float* s3 = ws + 3 * S;   // v, then ff chunk (13056*1024 == S)
    float* logits = ws + 4 * S;

    const dim3 blk(256);

    // ---- preprocess: x0 = concat([last_nv@Wnv+b, knn_nv, last_v@Wv+b, knn_v])
    pre_copy_k<<<BATCH * 100 * 64 / 256, 256, 0, stream>>>(xin, s0);
    {
        dim3 g(BATCH / 128, EMB / 128);
        gemm_k<false, true, false><<<g, blk, 0, stream>>>(
            xin + 50 * EMB, SEQL * EMB, Wnv, EMB, bnv, nullptr, 0, s0 + 0 * EMB, SEQL * EMB, EMB);
        gemm_k<false, true, false><<<g, blk, 0, stream>>>(
            xin + 101 * EMB, SEQL * EMB, Wvp, EMB, bvp, nullptr, 0, s0 + 51 * EMB, SEQL * EMB, EMB);
    }

    const dim3 g256(TOKENS / 128, EMB / 128);     // (408, 2)
    const dim3 gqkv(TOKENS / 128, 6);             // (408, 6)
    const dim3 gff1(MCHUNK / 128, FFD / 128);     // (102, 8)
    const dim3 gff2(MCHUNK / 128, EMB / 128);     // (102, 2)
    for (int l = 0; l < 3; ++l) {
        const float* wq  = Wq + (size_t)l * EMB * EMB;
        const float* wk  = Wk + (size_t)l * EMB * EMB;
        const float* wv  = Wv + (size_t)l * EMB * EMB;
        const float* wc  = Wc + (size_t)l * EMB * EMB;
        const float* bcl = bc + (size_t)l * EMB;
        const float* w1  = W1 + (size_t)l * EMB * FFD;
        const float* b1l = b1 + (size_t)l * FFD;
        const float* w2  = W2 + (size_t)l * FFD * EMB;
        const float* b2l = b2 + (size_t)l * EMB;

        qkv_k<<<gqkv, blk, 0, stream>>>(s0, wq, wk, wv, s1, s2, s3);

        attn_k<<<dim3(BATCH, NH), blk, 0, stream>>>(s1, s2, s3, s1);  // o aliases q

        // out1 = x + o@Wc + bc  -> s2 (k dead)
        gemm_k<false, true, true><<<g256, blk, 0, stream>>>(
            s1, EMB, wc, EMB, bcl, s0, EMB, s2, EMB, EMB);

        // FFN in 4 token chunks; ff intermediate reuses s3 (v dead).
        // x_next -> s0 (x dead after residual consumed above)
        for (int c = 0; c < 4; ++c) {
            const size_t moff = (size_t)c * MCHUNK;
            gemm_k<true, true, false><<<gff1, blk, 0, stream>>>(
                s2 + moff * EMB, EMB, w1, FFD, b1l, nullptr, 0, s3, FFD, EMB);
            gemm_k<false, true, true><<<gff2, blk, 0, stream>>>(
                s3, FFD, w2, EMB, b2l, s2 + moff * EMB, EMB, s0 + moff * EMB, EMB, FFD);
        }
    }

    logits_k<<<TOKENS / 4, 256, 0, stream>>>(s0, Wf, bfp, logits);
    final_k<<<BATCH, 128, 0, stream>>>(logits, mask, lastl, depotl, out);
}

// Round 10
// 2333.413 us; speedup vs baseline: 2.1213x; 1.9341x over previous
//
#include <hip/hip_runtime.h>
#include <math.h>

#define TOKENS 52224   // 512*102
#define SEQL   102
#define EMB    256
#define NH     16
#define DH     16
#define FFD    1024
#define BATCH  512
#define KS     50
#define POFF   1001    // problem_size + 1
#define MCHUNK 13056   // TOKENS/4 for FFN chunking
#define SCW    108

typedef short bf16x8 __attribute__((ext_vector_type(8)));
typedef float f32x4 __attribute__((ext_vector_type(4)));
typedef unsigned short ushort;
typedef unsigned int uint;

__device__ __forceinline__ ushort f2bf(float f) {
    union { float f; uint u; } c; c.f = f;
    uint u = c.u + 0x7FFFu + ((c.u >> 16) & 1u);
    return (ushort)(u >> 16);
}
__device__ __forceinline__ float bf2f(ushort h) {
    union { float f; uint u; } c; c.u = ((uint)h) << 16;
    return c.f;
}

// ---------------- weight pre-pack: fp32 W[K][N] -> hi/lo bf16 in MFMA frag order
// frag layout: elem j of lane l in chunk (kt,g):
//   k = kt*32 + (l>>4)*4 + (j&3) + 16*(j>>2),  n = g*16 + (l&15)
// packed offset = ((kt*Ng + g)*64 + l)*8 + j
__global__ __launch_bounds__(256)
void pack_k(const float* __restrict__ W, ushort* __restrict__ hi,
            ushort* __restrict__ lo, int N, int Ng)
{
    const int t = blockIdx.x * 256 + threadIdx.x;
    const int l = t & 63;
    const int g = (t >> 6) % Ng;
    const int kt = t / (64 * Ng);
    const int n = g * 16 + (l & 15);
    const int kb = kt * 32 + ((l >> 4) << 2);
    ushort h[8], lw[8];
    #pragma unroll
    for (int j = 0; j < 8; ++j) {
        const int k = kb + (j & 3) + ((j >> 2) << 4);
        const float v = W[(size_t)k * N + n];
        h[j] = f2bf(v);
        lw[j] = f2bf(v - bf2f(h[j]));
    }
    const size_t o = ((size_t)t) * 8;
    *(uint4*)&hi[o] = *(uint4*)h;
    *(uint4*)&lo[o] = *(uint4*)lw;
}

// ---------------- MFMA GEMM: C = relu?(A@W + bias) + res?, bf16x3 split ----
// BM=BN=128, BK=32, 4 waves (2x2 of 64x64). W pre-packed hi/lo.
template<bool RELU, bool HASBIAS, bool HASRES>
__device__ __forceinline__
void mgemm_body(const float* __restrict__ A, int lda,
                const ushort* __restrict__ Wh, const ushort* __restrict__ Wl,
                int Ng,
                const float* __restrict__ bias,
                const float* __restrict__ res, int ldres,
                float* __restrict__ C, int ldc,
                int K, size_t bm, int bn)
{
    __shared__ __align__(16) ushort Ah[4096], Al[4096], Bh[4096], Bl[4096];
    const int tid = threadIdx.x;
    const int lane = tid & 63;
    const int w = tid >> 6;
    const int wm = (w >> 1) * 64;
    const int wn = (w & 1) * 64;

    f32x4 acc[4][4];
    #pragma unroll
    for (int i = 0; i < 4; ++i)
        #pragma unroll
        for (int j = 0; j < 4; ++j) acc[i][j] = f32x4{0.f, 0.f, 0.f, 0.f};

    const int am0 = tid >> 3;          // rows am0 + i*32
    const int akq = tid & 7;           // k-quad
    const int alo = (akq & 3) * 16;    // lane-slot base
    const int ajb = (akq >> 2) * 4;    // j base (0 or 4)

    const int nkt = K >> 5;
    for (int kt = 0; kt < nkt; ++kt) {
        // stage A: fp32 -> hi/lo bf16, fragment order
        #pragma unroll
        for (int i = 0; i < 4; ++i) {
            const int m = am0 + i * 32;
            const float4 av = *(const float4*)(A + (bm + m) * lda + kt * 32 + akq * 4);
            const ushort h0 = f2bf(av.x), h1 = f2bf(av.y), h2 = f2bf(av.z), h3 = f2bf(av.w);
            const ushort l0 = f2bf(av.x - bf2f(h0)), l1 = f2bf(av.y - bf2f(h1));
            const ushort l2 = f2bf(av.z - bf2f(h2)), l3 = f2bf(av.w - bf2f(h3));
            const int sl = (((m >> 4) * 64) + alo + (m & 15)) * 8 + ajb;
            uint2 hv, lv;
            hv.x = (uint)h0 | ((uint)h1 << 16); hv.y = (uint)h2 | ((uint)h3 << 16);
            lv.x = (uint)l0 | ((uint)l1 << 16); lv.y = (uint)l2 | ((uint)l3 << 16);
            *(uint2*)&Ah[sl] = hv;
            *(uint2*)&Al[sl] = lv;
        }
        // stage B: pre-packed, vector copy
        {
            const size_t cbase = ((size_t)kt * Ng + (bn >> 4)) * 512;
            #pragma unroll
            for (int p = 0; p < 2; ++p) {
                const int o = p * 2048 + tid * 8;
                *(uint4*)&Bh[o] = *(const uint4*)(Wh + cbase + o);
                *(uint4*)&Bl[o] = *(const uint4*)(Wl + cbase + o);
            }
        }
        __syncthreads();
        bf16x8 af[4][2], bg[4][2];
        #pragma unroll
        for (int f = 0; f < 4; ++f) {
            const int sa = (((wm >> 4) + f) * 64 + lane) * 8;
            af[f][0] = *(const bf16x8*)&Ah[sa];
            af[f][1] = *(const bf16x8*)&Al[sa];
            const int sb = (((wn >> 4) + f) * 64 + lane) * 8;
            bg[f][0] = *(const bf16x8*)&Bh[sb];
            bg[f][1] = *(const bf16x8*)&Bl[sb];
        }
        #pragma unroll
        for (int i = 0; i < 4; ++i)
            #pragma unroll
            for (int j = 0; j < 4; ++j) {
                acc[i][j] = __builtin_amdgcn_mfma_f32_16x16x32_bf16(af[i][0], bg[j][0], acc[i][j], 0, 0, 0);
                acc[i][j] = __builtin_amdgcn_mfma_f32_16x16x32_bf16(af[i][0], bg[j][1], acc[i][j], 0, 0, 0);
                acc[i][j] = __builtin_amdgcn_mfma_f32_16x16x32_bf16(af[i][1], bg[j][0], acc[i][j], 0, 0, 0);
            }
        __syncthreads();
    }

    // epilogue: D row = (lane>>4)*4 + r, col = lane&15 (m89-verified)
    const int col0 = lane & 15;
    const int row0 = (lane >> 4) * 4;
    #pragma unroll
    for (int i = 0; i < 4; ++i) {
        #pragma unroll
        for (int r = 0; r < 4; ++r) {
            const size_t row = bm + wm + i * 16 + row0 + r;
            #pragma unroll
            for (int j = 0; j < 4; ++j) {
                const int col = bn + wn + j * 16 + col0;
                float v = acc[i][j][r];
                if (HASBIAS) v += bias[col];
                if (RELU) v = fmaxf(v, 0.f);
                if (HASRES) v += res[row * ldres + col];
                C[row * ldc + col] = v;
            }
        }
    }
}

template<bool RELU, bool HASBIAS, bool HASRES>
__global__ __launch_bounds__(256, 2)
void mgemm_k(const float* __restrict__ A, int lda,
             const ushort* __restrict__ Wh, const ushort* __restrict__ Wl, int Ng,
             const float* __restrict__ bias,
             const float* __restrict__ res, int ldres,
             float* __restrict__ C, int ldc, int K)
{
    mgemm_body<RELU, HASBIAS, HASRES>(A, lda, Wh, Wl, Ng, bias, res, ldres,
                                      C, ldc, K, (size_t)blockIdx.x * 128,
                                      blockIdx.y * 128);
}

// Fused QKV (MFMA): grid (TOKENS/128, 6); y>>1 selects weight/output.
__global__ __launch_bounds__(256, 2)
void qkv_mfma_k(const float* __restrict__ x,
                const ushort* __restrict__ qh, const ushort* __restrict__ ql,
                const ushort* __restrict__ kh, const ushort* __restrict__ kl,
                const ushort* __restrict__ vh, const ushort* __restrict__ vl,
                float* __restrict__ q, float* __restrict__ k, float* __restrict__ v)
{
    const int wi = blockIdx.y >> 1;
    const int bn = (blockIdx.y & 1) * 128;
    const ushort* Wh = (wi == 0) ? qh : (wi == 1) ? kh : vh;
    const ushort* Wl = (wi == 0) ? ql : (wi == 1) ? kl : vl;
    float* C = (wi == 0) ? q : (wi == 1) ? k : v;
    mgemm_body<false, false, false>(x, EMB, Wh, Wl, 16, nullptr, nullptr, 0,
                                    C, EMB, EMB, (size_t)blockIdx.x * 128, bn);
}

// ---------------- fp32 GEMM (kept for the two tiny preprocess GEMMs) -------
template<bool RELU, bool HASBIAS, bool HASRES>
__global__ __launch_bounds__(256, 2)
void gemm_k(const float* __restrict__ A, int lda,
            const float* __restrict__ W, int ldw,
            const float* __restrict__ bias,
            const float* __restrict__ res, int ldres,
            float* __restrict__ C, int ldc, int K)
{
    __shared__ float As[32][132];
    __shared__ float Ws[32][132];
    const int tid = threadIdx.x;
    const int tx = tid & 15;
    const int ty = tid >> 4;
    const size_t bm = (size_t)blockIdx.x * 128;
    const int bn = blockIdx.y * 128;

    float acc[8][8];
    #pragma unroll
    for (int i = 0; i < 8; ++i)
        #pragma unroll
        for (int j = 0; j < 8; ++j) acc[i][j] = 0.f;

    for (int k0 = 0; k0 < K; k0 += 32) {
        #pragma unroll
        for (int i = 0; i < 4; ++i) {
            int f = tid + i * 256;
            int m = f >> 3;
            int kq = f & 7;
            const float4 av = *(const float4*)(A + (bm + m) * lda + (k0 + kq * 4));
            As[kq * 4 + 0][m] = av.x;
            As[kq * 4 + 1][m] = av.y;
            As[kq * 4 + 2][m] = av.z;
            As[kq * 4 + 3][m] = av.w;
        }
        #pragma unroll
        for (int i = 0; i < 4; ++i) {
            int f = tid + i * 256;
            int kk = f >> 5;
            int nq = f & 31;
            *(float4*)&Ws[kk][nq * 4] =
                *(const float4*)(W + (size_t)(k0 + kk) * ldw + bn + nq * 4);
        }
        __syncthreads();
        #pragma unroll
        for (int kk = 0; kk < 32; ++kk) {
            float a0[8], b0[8];
            *(float4*)&a0[0] = *(const float4*)&As[kk][ty * 4];
            *(float4*)&a0[4] = *(const float4*)&As[kk][64 + ty * 4];
            *(float4*)&b0[0] = *(const float4*)&Ws[kk][tx * 4];
            *(float4*)&b0[4] = *(const float4*)&Ws[kk][64 + tx * 4];
            #pragma unroll
            for (int i = 0; i < 8; ++i)
                #pragma unroll
                for (int j = 0; j < 8; ++j)
                    acc[i][j] = fmaf(a0[i], b0[j], acc[i][j]);
        }
        __syncthreads();
    }
    #pragma unroll
    for (int ih = 0; ih < 2; ++ih)
        #pragma unroll
        for (int i2 = 0; i2 < 4; ++i2) {
            const int i = ih * 4 + i2;
            const size_t row = bm + ih * 64 + ty * 4 + i2;
            #pragma unroll
            for (int jh = 0; jh < 2; ++jh) {
                const int colb = bn + jh * 64 + tx * 4;
                float4 vv;
                vv.x = acc[i][jh * 4 + 0]; vv.y = acc[i][jh * 4 + 1];
                vv.z = acc[i][jh * 4 + 2]; vv.w = acc[i][jh * 4 + 3];
                if (HASBIAS) {
                    const float4 bb = *(const float4*)(bias + colb);
                    vv.x += bb.x; vv.y += bb.y; vv.z += bb.z; vv.w += bb.w;
                }
                if (RELU) {
                    vv.x = fmaxf(vv.x, 0.f); vv.y = fmaxf(vv.y, 0.f);
                    vv.z = fmaxf(vv.z, 0.f); vv.w = fmaxf(vv.w, 0.f);
                }
                if (HASRES) {
                    const float4 rr = *(const float4*)(res + row * ldres + colb);
                    vv.x += rr.x; vv.y += rr.y; vv.z += rr.z; vv.w += rr.w;
                }
                *(float4*)(C + row * ldc + colb) = vv;
            }
        }
}

// ---------------- preprocess copy ----------------
__global__ __launch_bounds__(256)
void pre_copy_k(const float* __restrict__ xin, float* __restrict__ x0)
{
    int idx = blockIdx.x * 256 + threadIdx.x;
    int c = idx & 63;
    int r = idx >> 6;
    int si = r % 100;
    int b = r / 100;
    int s = (si < 50) ? si + 1 : si + 2;
    const float4 v = *(const float4*)(xin + ((size_t)b * SEQL + (s - 1)) * EMB + c * 4);
    *(float4*)(x0 + ((size_t)b * SEQL + s) * EMB + c * 4) = v;
}

// ---------------- attention (round-4 validated version) ----------------
__global__ __launch_bounds__(256)
void attn_k(const float* __restrict__ q, const float* __restrict__ k,
            const float* __restrict__ v, float* __restrict__ o)
{
    const int b = blockIdx.x, h = blockIdx.y;
    __shared__ float qs[SEQL][DH];
    __shared__ float ksT[DH][104];
    __shared__ float vs[SEQL][DH];
    __shared__ float sc[SEQL][SCW];
    const size_t base = (size_t)b * SEQL * EMB + h * DH;
    const int tid = threadIdx.x;

    for (int idx = tid; idx < SEQL * DH; idx += 256) {
        int s = idx >> 4, d = idx & 15;
        float kv = k[base + (size_t)s * EMB + d];
        qs[s][d] = q[base + (size_t)s * EMB + d] * 0.25f;
        vs[s][d] = v[base + (size_t)s * EMB + d];
        ksT[d][s] = kv;
    }
    if (tid < DH * 2) ksT[tid >> 1][SEQL + (tid & 1)] = 0.f;
    __syncthreads();

    for (int t = tid; t < 51 * 26; t += 256) {
        int mp = t / 26;
        int n0 = (t - mp * 26) * 4;
        float4 a0 = {0.f, 0.f, 0.f, 0.f};
        float4 a1 = {0.f, 0.f, 0.f, 0.f};
        #pragma unroll
        for (int d = 0; d < DH; ++d) {
            const float4 kv = *(const float4*)&ksT[d][n0];
            const float q0 = qs[mp][d];
            const float q1 = qs[mp + 51][d];
            a0.x = fmaf(q0, kv.x, a0.x); a0.y = fmaf(q0, kv.y, a0.y);
            a0.z = fmaf(q0, kv.z, a0.z); a0.w = fmaf(q0, kv.w, a0.w);
            a1.x = fmaf(q1, kv.x, a1.x); a1.y = fmaf(q1, kv.y, a1.y);
            a1.z = fmaf(q1, kv.z, a1.z); a1.w = fmaf(q1, kv.w, a1.w);
        }
        *(float4*)&sc[mp][n0] = a0;
        *(float4*)&sc[mp + 51][n0] = a1;
    }
    __syncthreads();

    {
        const int grp = tid >> 5;
        const int lane = tid & 31;
        for (int m = grp; m < SEQL; m += 8) {
            float v0 = sc[m][lane];
            float v1 = sc[m][lane + 32];
            float v2 = sc[m][lane + 64];
            float v3 = (lane < SEQL - 96) ? sc[m][lane + 96] : -1e30f;
            float mx = fmaxf(fmaxf(v0, v1), fmaxf(v2, v3));
            #pragma unroll
            for (int s2 = 16; s2 > 0; s2 >>= 1) mx = fmaxf(mx, __shfl_xor(mx, s2));
            float e0 = __expf(v0 - mx);
            float e1 = __expf(v1 - mx);
            float e2 = __expf(v2 - mx);
            float e3 = (lane < SEQL - 96) ? __expf(v3 - mx) : 0.f;
            float sm = e0 + e1 + e2 + e3;
            #pragma unroll
            for (int s2 = 16; s2 > 0; s2 >>= 1) sm += __shfl_xor(sm, s2);
            const float inv = 1.f / sm;
            sc[m][lane] = e0 * inv;
            sc[m][lane + 32] = e1 * inv;
            sc[m][lane + 64] = e2 * inv;
            if (lane < SEQL - 96) sc[m][lane + 96] = e3 * inv;
        }
    }
    __syncthreads();

    for (int t = tid; t < 51 * 4; t += 256) {
        int mp = t >> 2;
        int d0 = (t & 3) * 4;
        float4 a0 = {0.f, 0.f, 0.f, 0.f};
        float4 a1 = {0.f, 0.f, 0.f, 0.f};
        for (int n = 0; n < SEQL; ++n) {
            const float4 vv = *(const float4*)&vs[n][d0];
            const float p0 = sc[mp][n];
            const float p1 = sc[mp + 51][n];
            a0.x = fmaf(p0, vv.x, a0.x); a0.y = fmaf(p0, vv.y, a0.y);
            a0.z = fmaf(p0, vv.z, a0.z); a0.w = fmaf(p0, vv.w, a0.w);
            a1.x = fmaf(p1, vv.x, a1.x); a1.y = fmaf(p1, vv.y, a1.y);
            a1.z = fmaf(p1, vv.z, a1.z); a1.w = fmaf(p1, vv.w, a1.w);
        }
        *(float4*)(o + base + (size_t)mp * EMB + d0) = a0;
        *(float4*)(o + base + (size_t)(mp + 51) * EMB + d0) = a1;
    }
}

// ---------------- logits ----------------
__global__ __launch_bounds__(256)
void logits_k(const float* __restrict__ x, const float* __restrict__ Wf,
              const float* __restrict__ bf, float* __restrict__ logits)
{
    const int t = blockIdx.x * 4 + (threadIdx.x >> 6);
    const int lane = threadIdx.x & 63;
    const float* row = x + (size_t)t * EMB;
    float s = 0.f;
    #pragma unroll
    for (int i = 0; i < 4; ++i) s = fmaf(row[lane + i * 64], Wf[lane + i * 64], s);
    #pragma unroll
    for (int off = 32; off > 0; off >>= 1) s += __shfl_down(s, off);
    if (lane == 0) logits[t] = s + bf[0];
}

// ---------------- final masked softmax + scatter ----------------
__global__ __launch_bounds__(128)
void final_k(const float* __restrict__ logits, const float* __restrict__ mask,
             const int* __restrict__ lastl, const int* __restrict__ depotl,
             float* __restrict__ out)
{
    const int b = blockIdx.x;
    const int tid = threadIdx.x;
    __shared__ float ls[SEQL];
    __shared__ float red[2];
    float v = 0.f;
    if (tid < SEQL) {
        v = logits[b * SEQL + tid];
        if (tid == 0 || tid == 51) v = -1e30f;
        else if (tid <= 50) v += mask[b * KS + (tid - 1)];
        ls[tid] = v;
    }
    __syncthreads();
    if (tid < 64) {
        float m = ls[tid];
        if (tid + 64 < SEQL) m = fmaxf(m, ls[tid + 64]);
        #pragma unroll
        for (int off = 32; off > 0; off >>= 1) m = fmaxf(m, __shfl_down(m, off));
        if (tid == 0) red[0] = m;
    }
    __syncthreads();
    const float mx = red[0];
    if (tid < SEQL) {
        float e = (tid == 0 || tid == 51) ? 0.f : expf(v - mx);
        ls[tid] = e;
    }
    __syncthreads();
    if (tid < 64) {
        float s2 = ls[tid];
        if (tid + 64 < SEQL) s2 += ls[tid + 64];
        #pragma unroll
        for (int off = 32; off > 0; off >>= 1) s2 += __shfl_down(s2, off);
        if (tid == 0) red[1] = s2;
    }
    __syncthreads();
    const float sum = red[1];
    float* orow = out + (size_t)b * 2002;
    for (int j = tid; j < 2002; j += 128) orow[j] = 1e-20f;
    __syncthreads();
    if (tid < SEQL && tid != 0 && tid != 51) {
        float p = ls[tid] / sum;
        if (p <= 1e-5f) p += 1e-7f;
        int col;
        if (tid <= 50) col = lastl[b * KS + (tid - 1)];
        else           col = POFF + depotl[b * KS + (tid - 52)];
        orow[col] = p;
    }
}

extern "C" void kernel_launch(void* const* d_in, const int* in_sizes, int n_in,
                              void* d_out, int out_size, void* d_ws, size_t ws_size,
                              hipStream_t stream)
{
    const float* xin  = (const float*)d_in[0];
    const float* mask = (const float*)d_in[1];
    const float* Wnv  = (const float*)d_in[2];
    const float* bnv  = (const float*)d_in[3];
    const float* Wvp  = (const float*)d_in[4];
    const float* bvp  = (const float*)d_in[5];
    const float* Wq   = (const float*)d_in[6];
    const float* Wk   = (const float*)d_in[7];
    const float* Wv   = (const float*)d_in[8];
    const float* Wc   = (const float*)d_in[9];
    const float* bc   = (const float*)d_in[10];
    const float* W1   = (const float*)d_in[11];
    const float* b1   = (const float*)d_in[12];
    const float* W2   = (const float*)d_in[13];
    const float* b2   = (const float*)d_in[14];
    const float* Wf   = (const float*)d_in[15];
    const float* bfp  = (const float*)d_in[16];
    const int* lastl  = (const int*)d_in[17];
    const int* depotl = (const int*)d_in[18];
    float* out = (float*)d_out;

    float* ws = (float*)d_ws;
    const size_t S = (size_t)TOKENS * EMB;
    float* s0 = ws + 0 * S;
    float* s1 = ws + 1 * S;
    float* s2 = ws + 2 * S;
    float* s3 = ws + 3 * S;
    float* logits = ws + 4 * S;
    // packed weights: per layer 1,572,864 ushorts (3 MB); total ~9.4 MB
    ushort* pk = (ushort*)(ws + 4 * S + 65536);
    const size_t PER = 1572864;
    // per-layer offsets (ushorts): Wq 0, Wk 131072, Wv 262144, Wc 393216,
    // W1 524288, W2 1048576 (each block = hi then lo)

    const dim3 blk(256);

    // ---- weight pre-pack (12 dispatches) ----
    for (int l = 0; l < 3; ++l) {
        ushort* base = pk + l * PER;
        pack_k<<<32, blk, 0, stream>>>(Wq + (size_t)l * EMB * EMB, base + 0, base + 65536, EMB, 16);
        pack_k<<<32, blk, 0, stream>>>(Wk + (size_t)l * EMB * EMB, base + 131072, base + 196608, EMB, 16);
        pack_k<<<32, blk, 0, stream>>>(Wv + (size_t)l * EMB * EMB, base + 262144, base + 327680, EMB, 16);
        pack_k<<<32, blk, 0, stream>>>(Wc + (size_t)l * EMB * EMB, base + 393216, base + 458752, EMB, 16);
        pack_k<<<128, blk, 0, stream>>>(W1 + (size_t)l * EMB * FFD, base + 524288, base + 786432, FFD, 64);
        pack_k<<<128, blk, 0, stream>>>(W2 + (size_t)l * FFD * EMB, base + 1048576, base + 1310720, EMB, 16);
    }

    // ---- preprocess ----
    pre_copy_k<<<BATCH * 100 * 64 / 256, 256, 0, stream>>>(xin, s0);
    {
        dim3 g(BATCH / 128, EMB / 128);
        gemm_k<false, true, false><<<g, blk, 0, stream>>>(
            xin + 50 * EMB, SEQL * EMB, Wnv, EMB, bnv, nullptr, 0, s0 + 0 * EMB, SEQL * EMB, EMB);
        gemm_k<false, true, false><<<g, blk, 0, stream>>>(
            xin + 101 * EMB, SEQL * EMB, Wvp, EMB, bvp, nullptr, 0, s0 + 51 * EMB, SEQL * EMB, EMB);
    }

    const dim3 g256(TOKENS / 128, EMB / 128);     // (408, 2)
    const dim3 gqkv(TOKENS / 128, 6);             // (408, 6)
    const dim3 gff1(MCHUNK / 128, FFD / 128);     // (102, 8)
    const dim3 gff2(MCHUNK / 128, EMB / 128);     // (102, 2)
    for (int l = 0; l < 3; ++l) {
        ushort* base = pk + l * PER;
        const float* bcl = bc + (size_t)l * EMB;
        const float* b1l = b1 + (size_t)l * FFD;
        const float* b2l = b2 + (size_t)l * EMB;

        qkv_mfma_k<<<gqkv, blk, 0, stream>>>(
            s0, base + 0, base + 65536, base + 131072, base + 196608,
            base + 262144, base + 327680, s1, s2, s3);

        attn_k<<<dim3(BATCH, NH), blk, 0, stream>>>(s1, s2, s3, s1);  // o aliases q

        // out1 = x + o@Wc + bc -> s2
        mgemm_k<false, true, true><<<g256, blk, 0, stream>>>(
            s1, EMB, base + 393216, base + 458752, 16, bcl, s0, EMB, s2, EMB, EMB);

        // FFN chunks: relu(out1@W1+b1) -> s3; out1 + ff@W2+b2 -> s0
        for (int c = 0; c < 4; ++c) {
            const size_t moff = (size_t)c * MCHUNK;
            mgemm_k<true, true, false><<<gff1, blk, 0, stream>>>(
                s2 + moff * EMB, EMB, base + 524288, base + 786432, 64, b1l,
                nullptr, 0, s3, FFD, EMB);
            mgemm_k<false, true, true><<<gff2, blk, 0, stream>>>(
                s3, FFD, base + 1048576, base + 1310720, 16, b2l,
                s2 + moff * EMB, EMB, s0 + moff * EMB, EMB, FFD);
        }
    }

    logits_k<<<TOKENS / 4, 256, 0, stream>>>(s0, Wf, bfp, logits);
    final_k<<<BATCH, 128, 0, stream>>>(logits, mask, lastl, depotl, out);
}